// Round 1
// baseline (844.632 us; speedup 1.0000x reference)
//
#include <hip/hip_runtime.h>
#include <hip/hip_bf16.h>

#define NTOK 6272   // T*H*W = 8*784
#define HW   784
#define NB   4      // batches

typedef __bf16 bf16x8 __attribute__((ext_vector_type(8)));
typedef float  f32x4  __attribute__((ext_vector_type(4)));

__device__ __forceinline__ f32x4 mfma16(bf16x8 a, bf16x8 b, f32x4 c) {
    return __builtin_amdgcn_mfma_f32_16x16x32_bf16(a, b, c, 0, 0, 0);
}

// ---------- phase 0: transpose proj weights to (c,o) f32; embed_w -> bf16 ----------
__global__ void prep_kernel(const float* __restrict__ tw, const float* __restrict__ pw,
                            const float* __restrict__ gw, const float* __restrict__ ew,
                            float* __restrict__ wT, __hip_bfloat16* __restrict__ EWb) {
    int gid = blockIdx.x * 256 + threadIdx.x;
    if (gid < 3 * 32768) {
        int m = gid >> 15;
        int r = gid & 32767;
        int o = r >> 8;      // 0..127
        int c = r & 255;     // 0..255
        const float* src = (m == 0) ? tw : (m == 1) ? pw : gw;
        wT[m * 32768 + c * 128 + o] = src[o * 256 + c];
    } else {
        int j = gid - 3 * 32768;
        if (j < 32768) EWb[j] = __float2bfloat16(ew[j]);
    }
}

// ---------- phase 1: theta/phi/g projections ----------
// Q,K: (b, N, 128) bf16 row-major.  VT: (b, 128, N) bf16 (g is naturally channel-major).
__global__ void __launch_bounds__(256)
proj_kernel(const float* __restrict__ feat, const float* __restrict__ wT,
            const float* __restrict__ tb, const float* __restrict__ pb,
            const float* __restrict__ gb,
            __hip_bfloat16* __restrict__ Q, __hip_bfloat16* __restrict__ K,
            __hip_bfloat16* __restrict__ VT) {
    __shared__ float xt[256][16];
    int blk = blockIdx.x;          // NB * 8 * 49
    int bi = blk / 392;
    int rem = blk % 392;
    int t = rem / 49;
    int chunk = rem % 49;
    int s0 = chunk * 16;
    int tid = threadIdx.x;

    const float* fb = feat + ((size_t)(bi * 8 + t) * 256) * HW + s0;
    {
        int sl = tid & 15, cg = tid >> 4;
        for (int c = cg; c < 256; c += 16)
            xt[c][sl] = fb[(size_t)c * HW + sl];
    }
    __syncthreads();

    int o = tid & 127, half = tid >> 7;
    float at[8], ap[8], ag[8];
#pragma unroll
    for (int i = 0; i < 8; i++) { at[i] = 0.f; ap[i] = 0.f; ag[i] = 0.f; }

    for (int c = 0; c < 256; c++) {
        float w0 = wT[c * 128 + o];
        float w1 = wT[32768 + c * 128 + o];
        float w2 = wT[65536 + c * 128 + o];
        const float* xr = &xt[c][half * 8];
#pragma unroll
        for (int i = 0; i < 8; i++) {
            float x = xr[i];
            at[i] = fmaf(w0, x, at[i]);
            ap[i] = fmaf(w1, x, ap[i]);
            ag[i] = fmaf(w2, x, ag[i]);
        }
    }

    int n0 = t * HW + s0 + half * 8;
    size_t bq = (size_t)bi * NTOK * 128;
    float b0 = tb[o], b1 = pb[o], b2 = gb[o];
#pragma unroll
    for (int i = 0; i < 8; i++) {
        Q[bq + (size_t)(n0 + i) * 128 + o] = __float2bfloat16(at[i] + b0);
        K[bq + (size_t)(n0 + i) * 128 + o] = __float2bfloat16(ap[i] + b1);
    }
#pragma unroll
    for (int i = 0; i < 8; i++)
        VT[bq + (size_t)o * NTOK + n0 + i] = __float2bfloat16(ag[i] + b2);
}

// ---------- phase 2: flash attention ----------
// Block: 2 waves, each wave owns 32 q-rows (2 row-tiles). QBLK=64, KBLK=64.
__global__ void __launch_bounds__(128)
attn_kernel(const __hip_bfloat16* __restrict__ Qg, const __hip_bfloat16* __restrict__ Kg,
            const __hip_bfloat16* __restrict__ Vg, __hip_bfloat16* __restrict__ Obf) {
    __shared__ alignas(16) __hip_bfloat16 Kt[64][136];   // keys x channels (+8 pad)
    __shared__ alignas(16) __hip_bfloat16 Vt[128][72];   // channels x keys (+8 pad)
    __shared__ alignas(16) __hip_bfloat16 Pl[2][32][72]; // per-wave P staging

    int bi = blockIdx.x / 98;
    int qc = blockIdx.x % 98;
    int qbase = qc * 64;
    int tid = threadIdx.x;
    int w = tid >> 6;
    int lane = tid & 63;
    int ln = lane & 15, g = lane >> 4;

    const __hip_bfloat16* Qb = Qg + (size_t)bi * NTOK * 128;
    const __hip_bfloat16* Kb = Kg + (size_t)bi * NTOK * 128;
    const __hip_bfloat16* Vb = Vg + (size_t)bi * NTOK * 128;  // (128, NTOK)
    __hip_bfloat16* Ob = Obf + (size_t)bi * NTOK * 128;

    // Q fragments in registers: A layout row = ln, k = ks*32 + g*8 + i
    bf16x8 qf[2][4];
#pragma unroll
    for (int rt = 0; rt < 2; rt++)
#pragma unroll
        for (int ks = 0; ks < 4; ks++)
            qf[rt][ks] = *reinterpret_cast<const bf16x8*>(
                &Qb[(size_t)(qbase + w * 32 + rt * 16 + ln) * 128 + ks * 32 + g * 8]);

    float m_run[2][4], l_run[2][4];
    f32x4 oacc[2][8];
#pragma unroll
    for (int rt = 0; rt < 2; rt++)
#pragma unroll
        for (int r = 0; r < 4; r++) { m_run[rt][r] = -1e30f; l_run[rt][r] = 0.f; }
#pragma unroll
    for (int rt = 0; rt < 2; rt++)
#pragma unroll
        for (int oc = 0; oc < 8; oc++) oacc[rt][oc] = (f32x4){0.f, 0.f, 0.f, 0.f};

    for (int nt = 0; nt < 98; nt++) {
        int kb = nt * 64;
        __syncthreads();
        // cooperative K tile load: 64 rows x 128 ch
#pragma unroll
        for (int i = 0; i < 8; i++) {
            int idx = i * 128 + tid;
            int r = idx >> 4, ch = idx & 15;
            *reinterpret_cast<bf16x8*>(&Kt[r][ch * 8]) =
                *reinterpret_cast<const bf16x8*>(&Kb[(size_t)(kb + r) * 128 + ch * 8]);
        }
        // cooperative V tile load: 128 ch rows x 64 keys
#pragma unroll
        for (int i = 0; i < 8; i++) {
            int idx = i * 128 + tid;
            int r = idx >> 3, ch = idx & 7;
            *reinterpret_cast<bf16x8*>(&Vt[r][ch * 8]) =
                *reinterpret_cast<const bf16x8*>(&Vb[(size_t)r * NTOK + kb + ch * 8]);
        }
        __syncthreads();

        // S = Q K^T : per wave 32x64 via 2 row-tiles
        f32x4 s[2][4];
#pragma unroll
        for (int rt = 0; rt < 2; rt++)
#pragma unroll
            for (int ct = 0; ct < 4; ct++) s[rt][ct] = (f32x4){0.f, 0.f, 0.f, 0.f};
#pragma unroll
        for (int ks = 0; ks < 4; ks++) {
#pragma unroll
            for (int ct = 0; ct < 4; ct++) {
                bf16x8 bk = *reinterpret_cast<const bf16x8*>(&Kt[ct * 16 + ln][ks * 32 + g * 8]);
                s[0][ct] = mfma16(qf[0][ks], bk, s[0][ct]);
                s[1][ct] = mfma16(qf[1][ks], bk, s[1][ct]);
            }
        }

        // online softmax per row (C/D layout: row = g*4 + r, col = ct*16 + ln)
#pragma unroll
        for (int rt = 0; rt < 2; rt++) {
#pragma unroll
            for (int r = 0; r < 4; r++) {
                float mt = fmaxf(fmaxf(s[rt][0][r], s[rt][1][r]),
                                 fmaxf(s[rt][2][r], s[rt][3][r]));
                mt = fmaxf(mt, __shfl_xor(mt, 1));
                mt = fmaxf(mt, __shfl_xor(mt, 2));
                mt = fmaxf(mt, __shfl_xor(mt, 4));
                mt = fmaxf(mt, __shfl_xor(mt, 8));
                float mnew = fmaxf(m_run[rt][r], mt);
                float corr = __expf(m_run[rt][r] - mnew);
                m_run[rt][r] = mnew;
                float ps = 0.f;
#pragma unroll
                for (int ct = 0; ct < 4; ct++) {
                    float p = __expf(s[rt][ct][r] - mnew);
                    s[rt][ct][r] = p;
                    ps += p;
                }
                ps += __shfl_xor(ps, 1);
                ps += __shfl_xor(ps, 2);
                ps += __shfl_xor(ps, 4);
                ps += __shfl_xor(ps, 8);
                l_run[rt][r] = l_run[rt][r] * corr + ps;
#pragma unroll
                for (int oc = 0; oc < 8; oc++) oacc[rt][oc][r] *= corr;
#pragma unroll
                for (int ct = 0; ct < 4; ct++)
                    Pl[w][rt * 16 + g * 4 + r][ct * 16 + ln] = __float2bfloat16(s[rt][ct][r]);
            }
        }
        __syncthreads();  // safety: drain P LDS writes before A-layout reads

        // O += P @ V
#pragma unroll
        for (int ks = 0; ks < 2; ks++) {
            bf16x8 pa0 = *reinterpret_cast<const bf16x8*>(&Pl[w][ln][ks * 32 + g * 8]);
            bf16x8 pa1 = *reinterpret_cast<const bf16x8*>(&Pl[w][16 + ln][ks * 32 + g * 8]);
#pragma unroll
            for (int oc = 0; oc < 8; oc++) {
                bf16x8 vb = *reinterpret_cast<const bf16x8*>(&Vt[oc * 16 + ln][ks * 32 + g * 8]);
                oacc[0][oc] = mfma16(pa0, vb, oacc[0][oc]);
                oacc[1][oc] = mfma16(pa1, vb, oacc[1][oc]);
            }
        }
    }

    // epilogue: O normalized, bf16 (N,128)
#pragma unroll
    for (int rt = 0; rt < 2; rt++)
#pragma unroll
        for (int oc = 0; oc < 8; oc++)
#pragma unroll
            for (int r = 0; r < 4; r++) {
                float v = oacc[rt][oc][r] / l_run[rt][r];
                int qrow = qbase + w * 32 + rt * 16 + g * 4 + r;
                Ob[(size_t)qrow * 128 + oc * 16 + ln] = __float2bfloat16(v);
            }
}

// ---------- phase 3: out = embed_w @ y + embed_b + feat ----------
__global__ void __launch_bounds__(256)
embed_kernel(const __hip_bfloat16* __restrict__ EWb, const __hip_bfloat16* __restrict__ Obf,
             const float* __restrict__ eb, const float* __restrict__ feat,
             float* __restrict__ out) {
    int bi = blockIdx.x / 98;
    int nc = blockIdx.x % 98;
    int nbase = nc * 64;
    int tid = threadIdx.x;
    int w = tid >> 6, lane = tid & 63, ln = lane & 15, g = lane >> 4;
    const __hip_bfloat16* Ob = Obf + (size_t)bi * NTOK * 128;

    f32x4 acc[4][4];
#pragma unroll
    for (int rt = 0; rt < 4; rt++)
#pragma unroll
        for (int ct = 0; ct < 4; ct++) acc[rt][ct] = (f32x4){0.f, 0.f, 0.f, 0.f};

#pragma unroll
    for (int ks = 0; ks < 4; ks++) {
        bf16x8 A[4], Bv[4];
#pragma unroll
        for (int rt = 0; rt < 4; rt++)
            A[rt] = *reinterpret_cast<const bf16x8*>(
                &EWb[(size_t)(w * 64 + rt * 16 + ln) * 128 + ks * 32 + g * 8]);
#pragma unroll
        for (int ct = 0; ct < 4; ct++)
            Bv[ct] = *reinterpret_cast<const bf16x8*>(
                &Ob[(size_t)(nbase + ct * 16 + ln) * 128 + ks * 32 + g * 8]);
#pragma unroll
        for (int rt = 0; rt < 4; rt++)
#pragma unroll
            for (int ct = 0; ct < 4; ct++)
                acc[rt][ct] = mfma16(A[rt], Bv[ct], acc[rt][ct]);
    }

#pragma unroll
    for (int rt = 0; rt < 4; rt++)
#pragma unroll
        for (int ct = 0; ct < 4; ct++)
#pragma unroll
            for (int r = 0; r < 4; r++) {
                int c = w * 64 + rt * 16 + g * 4 + r;
                int n = nbase + ct * 16 + ln;
                int t = n / HW, sp = n % HW;
                size_t idx = ((size_t)(bi * 8 + t) * 256 + c) * HW + sp;
                out[idx] = feat[idx] + acc[rt][ct][r] + eb[c];
            }
}

extern "C" void kernel_launch(void* const* d_in, const int* in_sizes, int n_in,
                              void* d_out, int out_size, void* d_ws, size_t ws_size,
                              hipStream_t stream) {
    const float* feat = (const float*)d_in[0];
    const float* tw   = (const float*)d_in[1];
    const float* tb   = (const float*)d_in[2];
    const float* pw   = (const float*)d_in[3];
    const float* pb   = (const float*)d_in[4];
    const float* gw   = (const float*)d_in[5];
    const float* gb   = (const float*)d_in[6];
    const float* ew   = (const float*)d_in[7];
    const float* eb   = (const float*)d_in[8];
    float* out = (float*)d_out;

    const size_t NE = (size_t)NB * NTOK * 128;  // 3,211,264 elems per buffer
    __hip_bfloat16* Q   = (__hip_bfloat16*)d_ws;
    __hip_bfloat16* K   = Q + NE;
    __hip_bfloat16* VT  = K + NE;
    __hip_bfloat16* Obf = VT + NE;
    float* wT = (float*)(Obf + NE);
    __hip_bfloat16* EWb = (__hip_bfloat16*)(wT + 3 * 32768);

    prep_kernel<<<512, 256, 0, stream>>>(tw, pw, gw, ew, wT, EWb);
    proj_kernel<<<NB * 8 * 49, 256, 0, stream>>>(feat, wT, tb, pb, gb, Q, K, VT);
    attn_kernel<<<NB * 98, 128, 0, stream>>>(Q, K, VT, Obf);
    embed_kernel<<<NB * 98, 256, 0, stream>>>(EWb, Obf, eb, feat, out);
}

// Round 2
// 330.805 us; speedup vs baseline: 2.5533x; 2.5533x over previous
//
#include <hip/hip_runtime.h>
#include <hip/hip_bf16.h>

#define NTOK 6272   // T*H*W = 8*784
#define HW   784
#define NB   4      // batches
#define NROW (NB * NTOK)   // 25088 total q-rows

typedef __bf16 bf16x8 __attribute__((ext_vector_type(8)));
typedef float  f32x4  __attribute__((ext_vector_type(4)));

__device__ __forceinline__ f32x4 mfma16(bf16x8 a, bf16x8 b, f32x4 c) {
    return __builtin_amdgcn_mfma_f32_16x16x32_bf16(a, b, c, 0, 0, 0);
}

// ---------- phase 0: transpose proj weights to (c,o) f32; embed_w -> bf16 ----------
__global__ void prep_kernel(const float* __restrict__ tw, const float* __restrict__ pw,
                            const float* __restrict__ gw, const float* __restrict__ ew,
                            float* __restrict__ wT, __hip_bfloat16* __restrict__ EWb) {
    int gid = blockIdx.x * 256 + threadIdx.x;
    if (gid < 3 * 32768) {
        int m = gid >> 15;
        int r = gid & 32767;
        int o = r >> 8;      // 0..127
        int c = r & 255;     // 0..255
        const float* src = (m == 0) ? tw : (m == 1) ? pw : gw;
        wT[m * 32768 + c * 128 + o] = src[o * 256 + c];
    } else {
        int j = gid - 3 * 32768;
        if (j < 32768) EWb[j] = __float2bfloat16(ew[j]);
    }
}

// ---------- phase 1: theta/phi/g projections ----------
__global__ void __launch_bounds__(256)
proj_kernel(const float* __restrict__ feat, const float* __restrict__ wT,
            const float* __restrict__ tb, const float* __restrict__ pb,
            const float* __restrict__ gb,
            __hip_bfloat16* __restrict__ Q, __hip_bfloat16* __restrict__ K,
            __hip_bfloat16* __restrict__ VT) {
    __shared__ float xt[256][16];
    int blk = blockIdx.x;          // NB * 8 * 49
    int bi = blk / 392;
    int rem = blk % 392;
    int t = rem / 49;
    int chunk = rem % 49;
    int s0 = chunk * 16;
    int tid = threadIdx.x;

    const float* fb = feat + ((size_t)(bi * 8 + t) * 256) * HW + s0;
    {
        int sl = tid & 15, cg = tid >> 4;
        for (int c = cg; c < 256; c += 16)
            xt[c][sl] = fb[(size_t)c * HW + sl];
    }
    __syncthreads();

    int o = tid & 127, half = tid >> 7;
    float at[8], ap[8], ag[8];
#pragma unroll
    for (int i = 0; i < 8; i++) { at[i] = 0.f; ap[i] = 0.f; ag[i] = 0.f; }

    for (int c = 0; c < 256; c++) {
        float w0 = wT[c * 128 + o];
        float w1 = wT[32768 + c * 128 + o];
        float w2 = wT[65536 + c * 128 + o];
        const float* xr = &xt[c][half * 8];
#pragma unroll
        for (int i = 0; i < 8; i++) {
            float x = xr[i];
            at[i] = fmaf(w0, x, at[i]);
            ap[i] = fmaf(w1, x, ap[i]);
            ag[i] = fmaf(w2, x, ag[i]);
        }
    }

    int n0 = t * HW + s0 + half * 8;
    size_t bq = (size_t)bi * NTOK * 128;
    float b0 = tb[o], b1 = pb[o], b2 = gb[o];
#pragma unroll
    for (int i = 0; i < 8; i++) {
        Q[bq + (size_t)(n0 + i) * 128 + o] = __float2bfloat16(at[i] + b0);
        K[bq + (size_t)(n0 + i) * 128 + o] = __float2bfloat16(ap[i] + b1);
    }
#pragma unroll
    for (int i = 0; i < 8; i++)
        VT[bq + (size_t)o * NTOK + n0 + i] = __float2bfloat16(ag[i] + b2);
}

// ---------- phase 2: flash attention, split-K ----------
// Block: 4 waves x 16 q-rows (QBLK=64), KBLK=64.
// S = number of K-splits. S==1 writes normalized O directly to Out.
// S>1 writes per-split normalized O (bf16) + m,l (f32) for later merge.
template<int S>
__global__ void __launch_bounds__(256, 3)
attn_kernel(const __hip_bfloat16* __restrict__ Qg, const __hip_bfloat16* __restrict__ Kg,
            const __hip_bfloat16* __restrict__ Vg, __hip_bfloat16* __restrict__ Out,
            float* __restrict__ mpart, float* __restrict__ lpart) {
    __shared__ alignas(16) __hip_bfloat16 Kt[64][136];   // keys x channels (+8 pad)
    __shared__ alignas(16) __hip_bfloat16 Vt[128][72];   // channels x keys (+8 pad)
    __shared__ alignas(16) __hip_bfloat16 Pl[4][16][72]; // per-wave P staging

    int bid = blockIdx.x;                 // NB * 98 * S
    int s  = bid % S;
    int qc = (bid / S) % 98;
    int bi = bid / (S * 98);
    int qbase = qc * 64;
    int kt0 = (98 * s) / S, kt1 = (98 * (s + 1)) / S;

    int tid = threadIdx.x;
    int w = tid >> 6;
    int lane = tid & 63;
    int ln = lane & 15, g = lane >> 4;

    const __hip_bfloat16* Qb = Qg + (size_t)bi * NTOK * 128;
    const __hip_bfloat16* Kb = Kg + (size_t)bi * NTOK * 128;
    const __hip_bfloat16* Vb = Vg + (size_t)bi * NTOK * 128;  // (128, NTOK)

    // Q fragments: A layout row = ln, k = ks*32 + g*8 + i
    bf16x8 qf[4];
#pragma unroll
    for (int ks = 0; ks < 4; ks++)
        qf[ks] = *reinterpret_cast<const bf16x8*>(
            &Qb[(size_t)(qbase + w * 16 + ln) * 128 + ks * 32 + g * 8]);

    float m_run[4], l_run[4];
    f32x4 oacc[8];
#pragma unroll
    for (int r = 0; r < 4; r++) { m_run[r] = -1e30f; l_run[r] = 0.f; }
#pragma unroll
    for (int oc = 0; oc < 8; oc++) oacc[oc] = (f32x4){0.f, 0.f, 0.f, 0.f};

    for (int nt = kt0; nt < kt1; nt++) {
        int kb = nt * 64;
        __syncthreads();
        // cooperative K tile load: 64 rows x 128 ch (256 threads, 4 iters)
#pragma unroll
        for (int i = 0; i < 4; i++) {
            int idx = i * 256 + tid;
            int r = idx >> 4, ch = idx & 15;
            *reinterpret_cast<bf16x8*>(&Kt[r][ch * 8]) =
                *reinterpret_cast<const bf16x8*>(&Kb[(size_t)(kb + r) * 128 + ch * 8]);
        }
        // cooperative V tile load: 128 ch rows x 64 keys
#pragma unroll
        for (int i = 0; i < 4; i++) {
            int idx = i * 256 + tid;
            int r = idx >> 3, ch = idx & 7;
            *reinterpret_cast<bf16x8*>(&Vt[r][ch * 8]) =
                *reinterpret_cast<const bf16x8*>(&Vb[(size_t)r * NTOK + kb + ch * 8]);
        }
        __syncthreads();

        // S = Q K^T : per wave 16x64
        f32x4 sc[4];
#pragma unroll
        for (int ct = 0; ct < 4; ct++) sc[ct] = (f32x4){0.f, 0.f, 0.f, 0.f};
#pragma unroll
        for (int ks = 0; ks < 4; ks++) {
#pragma unroll
            for (int ct = 0; ct < 4; ct++) {
                bf16x8 bk = *reinterpret_cast<const bf16x8*>(&Kt[ct * 16 + ln][ks * 32 + g * 8]);
                sc[ct] = mfma16(qf[ks], bk, sc[ct]);
            }
        }

        // online softmax per row (C layout: row = g*4 + r, col = ct*16 + ln)
#pragma unroll
        for (int r = 0; r < 4; r++) {
            float mt = fmaxf(fmaxf(sc[0][r], sc[1][r]), fmaxf(sc[2][r], sc[3][r]));
            mt = fmaxf(mt, __shfl_xor(mt, 1));
            mt = fmaxf(mt, __shfl_xor(mt, 2));
            mt = fmaxf(mt, __shfl_xor(mt, 4));
            mt = fmaxf(mt, __shfl_xor(mt, 8));
            float mnew = fmaxf(m_run[r], mt);
            float corr = __expf(m_run[r] - mnew);
            m_run[r] = mnew;
            float ps = 0.f;
#pragma unroll
            for (int ct = 0; ct < 4; ct++) {
                float p = __expf(sc[ct][r] - mnew);
                sc[ct][r] = p;
                ps += p;
            }
            ps += __shfl_xor(ps, 1);
            ps += __shfl_xor(ps, 2);
            ps += __shfl_xor(ps, 4);
            ps += __shfl_xor(ps, 8);
            l_run[r] = l_run[r] * corr + ps;
#pragma unroll
            for (int oc = 0; oc < 8; oc++) oacc[oc][r] *= corr;
#pragma unroll
            for (int ct = 0; ct < 4; ct++)
                Pl[w][g * 4 + r][ct * 16 + ln] = __float2bfloat16(sc[ct][r]);
        }
        // no __syncthreads needed: Pl is per-wave; compiler orders LDS w->r.

        // O += P @ V
#pragma unroll
        for (int ks = 0; ks < 2; ks++) {
            bf16x8 pa = *reinterpret_cast<const bf16x8*>(&Pl[w][ln][ks * 32 + g * 8]);
#pragma unroll
            for (int oc = 0; oc < 8; oc++) {
                bf16x8 vb = *reinterpret_cast<const bf16x8*>(&Vt[oc * 16 + ln][ks * 32 + g * 8]);
                oacc[oc] = mfma16(pa, vb, oacc[oc]);
            }
        }
    }

    // epilogue: normalized O per split (C layout row = g*4 + r, col = oc*16 + ln)
    float inv[4];
#pragma unroll
    for (int r = 0; r < 4; r++) inv[r] = 1.f / l_run[r];

    size_t growbase = (size_t)bi * NTOK + qbase + w * 16 + g * 4;
    if (S == 1) {
#pragma unroll
        for (int oc = 0; oc < 8; oc++)
#pragma unroll
            for (int r = 0; r < 4; r++)
                Out[(growbase + r) * 128 + oc * 16 + ln] =
                    __float2bfloat16(oacc[oc][r] * inv[r]);
    } else {
#pragma unroll
        for (int oc = 0; oc < 8; oc++)
#pragma unroll
            for (int r = 0; r < 4; r++)
                Out[((size_t)s * NROW + growbase + r) * 128 + oc * 16 + ln] =
                    __float2bfloat16(oacc[oc][r] * inv[r]);
        if (ln == 0) {
#pragma unroll
            for (int r = 0; r < 4; r++) {
                mpart[s * NROW + growbase + r] = m_run[r];
                lpart[s * NROW + growbase + r] = l_run[r];
            }
        }
    }
}

// ---------- phase 2b: merge split-K partials ----------
template<int S>
__global__ void __launch_bounds__(256)
merge_kernel(const __hip_bfloat16* __restrict__ Opart, const float* __restrict__ mpart,
             const float* __restrict__ lpart, __hip_bfloat16* __restrict__ Obf) {
    int gid = blockIdx.x * 256 + threadIdx.x;   // NROW * 16
    int row = gid >> 4;
    int c0 = (gid & 15) * 8;

    float m = -1e30f;
#pragma unroll
    for (int s = 0; s < S; s++) m = fmaxf(m, mpart[s * NROW + row]);
    float wgt[S];
    float den = 0.f;
#pragma unroll
    for (int s = 0; s < S; s++) {
        wgt[s] = lpart[s * NROW + row] * __expf(mpart[s * NROW + row] - m);
        den += wgt[s];
    }
    float o[8];
#pragma unroll
    for (int j = 0; j < 8; j++) o[j] = 0.f;
#pragma unroll
    for (int s = 0; s < S; s++) {
        bf16x8 v = *reinterpret_cast<const bf16x8*>(
            &Opart[((size_t)s * NROW + row) * 128 + c0]);
#pragma unroll
        for (int j = 0; j < 8; j++) o[j] = fmaf(wgt[s], (float)v[j], o[j]);
    }
    float invden = 1.f / den;
    bf16x8 outv;
#pragma unroll
    for (int j = 0; j < 8; j++) outv[j] = (__bf16)(o[j] * invden);
    *reinterpret_cast<bf16x8*>(&Obf[(size_t)row * 128 + c0]) = outv;
}

// ---------- phase 3: out = embed_w @ y + embed_b + feat ----------
__global__ void __launch_bounds__(256)
embed_kernel(const __hip_bfloat16* __restrict__ EWb, const __hip_bfloat16* __restrict__ Obf,
             const float* __restrict__ eb, const float* __restrict__ feat,
             float* __restrict__ out) {
    int bi = blockIdx.x / 98;
    int nc = blockIdx.x % 98;
    int nbase = nc * 64;
    int tid = threadIdx.x;
    int w = tid >> 6, lane = tid & 63, ln = lane & 15, g = lane >> 4;
    const __hip_bfloat16* Ob = Obf + (size_t)bi * NTOK * 128;

    f32x4 acc[4][4];
#pragma unroll
    for (int rt = 0; rt < 4; rt++)
#pragma unroll
        for (int ct = 0; ct < 4; ct++) acc[rt][ct] = (f32x4){0.f, 0.f, 0.f, 0.f};

#pragma unroll
    for (int ks = 0; ks < 4; ks++) {
        bf16x8 A[4], Bv[4];
#pragma unroll
        for (int rt = 0; rt < 4; rt++)
            A[rt] = *reinterpret_cast<const bf16x8*>(
                &EWb[(size_t)(w * 64 + rt * 16 + ln) * 128 + ks * 32 + g * 8]);
#pragma unroll
        for (int ct = 0; ct < 4; ct++)
            Bv[ct] = *reinterpret_cast<const bf16x8*>(
                &Ob[(size_t)(nbase + ct * 16 + ln) * 128 + ks * 32 + g * 8]);
#pragma unroll
        for (int rt = 0; rt < 4; rt++)
#pragma unroll
            for (int ct = 0; ct < 4; ct++)
                acc[rt][ct] = mfma16(A[rt], Bv[ct], acc[rt][ct]);
    }

#pragma unroll
    for (int rt = 0; rt < 4; rt++)
#pragma unroll
        for (int ct = 0; ct < 4; ct++)
#pragma unroll
            for (int r = 0; r < 4; r++) {
                int c = w * 64 + rt * 16 + g * 4 + r;
                int n = nbase + ct * 16 + ln;
                int t = n / HW, sp = n % HW;
                size_t idx = ((size_t)(bi * 8 + t) * 256 + c) * HW + sp;
                out[idx] = feat[idx] + acc[rt][ct][r] + eb[c];
            }
}

extern "C" void kernel_launch(void* const* d_in, const int* in_sizes, int n_in,
                              void* d_out, int out_size, void* d_ws, size_t ws_size,
                              hipStream_t stream) {
    const float* feat = (const float*)d_in[0];
    const float* tw   = (const float*)d_in[1];
    const float* tb   = (const float*)d_in[2];
    const float* pw   = (const float*)d_in[3];
    const float* pb   = (const float*)d_in[4];
    const float* gw   = (const float*)d_in[5];
    const float* gb   = (const float*)d_in[6];
    const float* ew   = (const float*)d_in[7];
    const float* eb   = (const float*)d_in[8];
    float* out = (float*)d_out;

    const size_t NE = (size_t)NB * NTOK * 128;  // 3,211,264 elems per buffer
    __hip_bfloat16* Q   = (__hip_bfloat16*)d_ws;
    __hip_bfloat16* K   = Q + NE;
    __hip_bfloat16* VT  = K + NE;
    __hip_bfloat16* Obf = VT + NE;
    float* wT = (float*)(Obf + NE);
    __hip_bfloat16* EWb = (__hip_bfloat16*)(wT + 3 * 32768);
    __hip_bfloat16* Opart = EWb + 32768;

    const size_t base_bytes = (size_t)((char*)(Opart) - (char*)d_ws);
    const size_t per_split = (size_t)NROW * 128 * 2 + (size_t)NROW * 8;  // O + m + l
    int S = 1;
    if (ws_size >= base_bytes + 4 * per_split) S = 4;
    else if (ws_size >= base_bytes + 2 * per_split) S = 2;

    float* mpart = (float*)(Opart + (size_t)S * NROW * 128);
    float* lpart = mpart + (size_t)S * NROW;

    prep_kernel<<<512, 256, 0, stream>>>(tw, pw, gw, ew, wT, EWb);
    proj_kernel<<<NB * 8 * 49, 256, 0, stream>>>(feat, wT, tb, pb, gb, Q, K, VT);

    if (S == 4) {
        attn_kernel<4><<<NB * 98 * 4, 256, 0, stream>>>(Q, K, VT, Opart, mpart, lpart);
        merge_kernel<4><<<NROW * 16 / 256, 256, 0, stream>>>(Opart, mpart, lpart, Obf);
    } else if (S == 2) {
        attn_kernel<2><<<NB * 98 * 2, 256, 0, stream>>>(Q, K, VT, Opart, mpart, lpart);
        merge_kernel<2><<<NROW * 16 / 256, 256, 0, stream>>>(Opart, mpart, lpart, Obf);
    } else {
        attn_kernel<1><<<NB * 98, 256, 0, stream>>>(Q, K, VT, Obf, nullptr, nullptr);
    }

    embed_kernel<<<NB * 98, 256, 0, stream>>>(EWb, Obf, eb, feat, out);
}

// Round 3
// 283.088 us; speedup vs baseline: 2.9836x; 1.1686x over previous
//
#include <hip/hip_runtime.h>
#include <hip/hip_bf16.h>

#define NTOK 6272   // T*H*W = 8*784
#define HW   784
#define NB   4      // batches
#define NROW (NB * NTOK)   // 25088 total q-rows

typedef __bf16 bf16x8 __attribute__((ext_vector_type(8)));
typedef float  f32x4  __attribute__((ext_vector_type(4)));
typedef float  f32x16 __attribute__((ext_vector_type(16)));

__device__ __forceinline__ f32x4 mfma16(bf16x8 a, bf16x8 b, f32x4 c) {
    return __builtin_amdgcn_mfma_f32_16x16x32_bf16(a, b, c, 0, 0, 0);
}
__device__ __forceinline__ f32x16 mfma32(bf16x8 a, bf16x8 b, f32x16 c) {
    return __builtin_amdgcn_mfma_f32_32x32x16_bf16(a, b, c, 0, 0, 0);
}

#define GLDS(gsrc, ldst) \
    __builtin_amdgcn_global_load_lds((const __attribute__((address_space(1))) void*)(gsrc), \
        (__attribute__((address_space(3))) void*)(ldst), 16, 0, 0)

__device__ __forceinline__ unsigned pkbf(float a, float b) {
    __bf16 l = (__bf16)a, h = (__bf16)b;
    unsigned short ul, uh;
    __builtin_memcpy(&ul, &l, 2);
    __builtin_memcpy(&uh, &h, 2);
    return (unsigned)ul | ((unsigned)uh << 16);
}

// ---------- phase 0: transpose proj weights to (c,o) f32; embed_w -> bf16 ----------
__global__ void prep_kernel(const float* __restrict__ tw, const float* __restrict__ pw,
                            const float* __restrict__ gw, const float* __restrict__ ew,
                            float* __restrict__ wT, __hip_bfloat16* __restrict__ EWb) {
    int gid = blockIdx.x * 256 + threadIdx.x;
    if (gid < 3 * 32768) {
        int m = gid >> 15;
        int r = gid & 32767;
        int o = r >> 8;      // 0..127
        int c = r & 255;     // 0..255
        const float* src = (m == 0) ? tw : (m == 1) ? pw : gw;
        wT[m * 32768 + c * 128 + o] = src[o * 256 + c];
    } else {
        int j = gid - 3 * 32768;
        if (j < 32768) EWb[j] = __float2bfloat16(ew[j]);
    }
}

// ---------- phase 1: theta/phi/g projections ----------
// Q (scaled by log2(e)), K: (b, N, 128) bf16 row-major.  VT: (b, 128, N) bf16.
__global__ void __launch_bounds__(256)
proj_kernel(const float* __restrict__ feat, const float* __restrict__ wT,
            const float* __restrict__ tb, const float* __restrict__ pb,
            const float* __restrict__ gb,
            __hip_bfloat16* __restrict__ Q, __hip_bfloat16* __restrict__ K,
            __hip_bfloat16* __restrict__ VT) {
    __shared__ float xt[256][16];
    int blk = blockIdx.x;          // NB * 8 * 49
    int bi = blk / 392;
    int rem = blk % 392;
    int t = rem / 49;
    int chunk = rem % 49;
    int s0 = chunk * 16;
    int tid = threadIdx.x;

    const float* fb = feat + ((size_t)(bi * 8 + t) * 256) * HW + s0;
    {
        int sl = tid & 15, cg = tid >> 4;
        for (int c = cg; c < 256; c += 16)
            xt[c][sl] = fb[(size_t)c * HW + sl];
    }
    __syncthreads();

    int o = tid & 127, half = tid >> 7;
    float at[8], ap[8], ag[8];
#pragma unroll
    for (int i = 0; i < 8; i++) { at[i] = 0.f; ap[i] = 0.f; ag[i] = 0.f; }

    for (int c = 0; c < 256; c++) {
        float w0 = wT[c * 128 + o];
        float w1 = wT[32768 + c * 128 + o];
        float w2 = wT[65536 + c * 128 + o];
        const float* xr = &xt[c][half * 8];
#pragma unroll
        for (int i = 0; i < 8; i++) {
            float x = xr[i];
            at[i] = fmaf(w0, x, at[i]);
            ap[i] = fmaf(w1, x, ap[i]);
            ag[i] = fmaf(w2, x, ag[i]);
        }
    }

    int n0 = t * HW + s0 + half * 8;
    size_t bq = (size_t)bi * NTOK * 128;
    float b0 = tb[o], b1 = pb[o], b2 = gb[o];
#pragma unroll
    for (int i = 0; i < 8; i++) {
        Q[bq + (size_t)(n0 + i) * 128 + o] = __float2bfloat16((at[i] + b0) * 1.44269504f);
        K[bq + (size_t)(n0 + i) * 128 + o] = __float2bfloat16(ap[i] + b1);
    }
#pragma unroll
    for (int i = 0; i < 8; i++)
        VT[bq + (size_t)o * NTOK + n0 + i] = __float2bfloat16(ag[i] + b2);
}

// ---------- phase 2: flash attention, 32x32 swapped-QK^T, split-K ----------
// Block: 4 waves x 32 q-rows (QBLK=128), KBLK=64, double-buffered LDS.
template<int S>
__global__ void __launch_bounds__(256, 2)
attn_kernel(const __hip_bfloat16* __restrict__ Qg, const __hip_bfloat16* __restrict__ Kg,
            const __hip_bfloat16* __restrict__ Vg, __hip_bfloat16* __restrict__ Out,
            float* __restrict__ mpart, float* __restrict__ lpart) {
    __shared__ __hip_bfloat16 Kt[2][64 * 128];   // keys x channels, XOR-swizzled
    __shared__ __hip_bfloat16 Vt[2][128 * 64];   // channels x keys, XOR-swizzled

    int bid = blockIdx.x;          // NB * 49 * S
    int s   = bid % S;
    int qc  = (bid / S) % 49;
    int bi  = bid / (S * 49);
    int qbase = qc * 128;
    int kt0 = (98 * s) / S, kt1 = (98 * (s + 1)) / S;

    int tid  = threadIdx.x;
    int w    = tid >> 6;
    int lane = tid & 63;
    int q32  = lane & 31;
    int hi   = lane >> 5;
    int swz  = (q32 & 7) << 4;   // row-XOR swizzle mask for K/V reads

    const __hip_bfloat16* Qb = Qg + (size_t)bi * NTOK * 128;
    const __hip_bfloat16* Kb = Kg + (size_t)bi * NTOK * 128;
    const __hip_bfloat16* Vb = Vg + (size_t)bi * NTOK * 128;  // (128, NTOK)

    // Q B-fragments in registers: B[k=ch][col=q]: lane holds Q[q32][kk*16+hi*8 .. +7]
    bf16x8 qf[8];
    {
        const __hip_bfloat16* qrow = Qb + (size_t)(qbase + w * 32 + q32) * 128 + hi * 8;
#pragma unroll
        for (int kk = 0; kk < 8; kk++)
            qf[kk] = *reinterpret_cast<const bf16x8*>(qrow + kk * 16);
    }

    float m_run = -1e30f, l_run = 0.f;
    f32x16 oacc[4];
#pragma unroll
    for (int ct = 0; ct < 4; ct++) oacc[ct] = {};

    auto stage = [&](int c, int kb) {
        // K tile: 16KB = 16 segs of 1KB; wave w does segs w*4..w*4+3
#pragma unroll
        for (int i = 0; i < 4; i++) {
            int seg = w * 4 + i;
            int r = seg * 4 + (lane >> 4);       // key row 0..63
            int ch = lane & 15;                  // 16B chunk in row
            const __hip_bfloat16* src = Kb + (size_t)(kb + r) * 128 + ((ch ^ (r & 7)) * 8);
            GLDS(src, &Kt[c][seg * 512]);
        }
        // V tile: 16KB
#pragma unroll
        for (int i = 0; i < 4; i++) {
            int seg = w * 4 + i;
            int r = seg * 8 + (lane >> 3);       // channel row 0..127
            int ch = lane & 7;
            const __hip_bfloat16* src = Vb + (size_t)r * NTOK + kb + ((ch ^ (r & 7)) * 8);
            GLDS(src, &Vt[c][seg * 512]);
        }
    };

    int cur = 0;
    stage(0, kt0 * 64);
    for (int nt = kt0; nt < kt1; nt++) {
        __syncthreads();                          // staged tile [cur] ready
        if (nt + 1 < kt1) stage(cur ^ 1, (nt + 1) * 64);   // prefetch overlaps compute

        const char* Kc = (const char*)&Kt[cur][0];
        const char* Vc = (const char*)&Vt[cur][0];

        // S^T = K * Q^T : D[key][q], 2 key-tiles of 32
        f32x16 st0 = {}, st1 = {};
        __builtin_amdgcn_s_setprio(1);
#pragma unroll
        for (int kk = 0; kk < 8; kk++) {
            int inner = (kk * 32 + hi * 16) ^ swz;
            bf16x8 a0 = *reinterpret_cast<const bf16x8*>(Kc + (q32 * 256 + inner));
            bf16x8 a1 = *reinterpret_cast<const bf16x8*>(Kc + ((32 + q32) * 256 + inner));
            st0 = mfma32(a0, qf[kk], st0);
            st1 = mfma32(a1, qf[kk], st1);
        }
        __builtin_amdgcn_s_setprio(0);

        // in-register online softmax (log2 domain); lanes l, l^32 share q-row
        float mt = fmaxf(st0[0], st0[1]);
#pragma unroll
        for (int j = 2; j < 16; j += 2) mt = fmaxf(mt, fmaxf(st0[j], st0[j + 1]));
#pragma unroll
        for (int j = 0; j < 16; j += 2) mt = fmaxf(mt, fmaxf(st1[j], st1[j + 1]));
        mt = fmaxf(mt, __shfl_xor(mt, 32));

        if (!__all(mt - m_run <= 8.f)) {          // T13 defer-max
            float mnew = fmaxf(m_run, mt);
            float corr = exp2f(m_run - mnew);
            l_run *= corr;
            m_run = mnew;
#pragma unroll
            for (int ct = 0; ct < 4; ct++) oacc[ct] *= corr;
        }
        float ps = 0.f;
#pragma unroll
        for (int j = 0; j < 16; j++) { st0[j] = exp2f(st0[j] - m_run); ps += st0[j]; }
#pragma unroll
        for (int j = 0; j < 16; j++) { st1[j] = exp2f(st1[j] - m_run); ps += st1[j]; }
        ps += __shfl_xor(ps, 32);
        l_run += ps;

        // pack P into PV B-fragments: pf[sstep] = P^T[sstep*16 + hi*8 + 0..7][q32]
        bf16x8 pf[4];
#pragma unroll
        for (int ss = 0; ss < 4; ss++) {
            int R = (ss & 1) * 8;
            float e0, e1, e2, e3, e4, e5, e6, e7;
            if (ss < 2) { e0 = st0[R]; e1 = st0[R + 1]; e2 = st0[R + 2]; e3 = st0[R + 3];
                          e4 = st0[R + 4]; e5 = st0[R + 5]; e6 = st0[R + 6]; e7 = st0[R + 7]; }
            else        { e0 = st1[R]; e1 = st1[R + 1]; e2 = st1[R + 2]; e3 = st1[R + 3];
                          e4 = st1[R + 4]; e5 = st1[R + 5]; e6 = st1[R + 6]; e7 = st1[R + 7]; }
            unsigned A0 = pkbf(e0, e1);   // keys (0,1)+4hi  (within 16)
            unsigned A1 = pkbf(e2, e3);   // keys (2,3)+4hi
            unsigned A2 = pkbf(e4, e5);   // keys (8,9)+4hi
            unsigned A3 = pkbf(e6, e7);   // keys (10,11)+4hi
            unsigned oA0 = (unsigned)__shfl_xor((int)A0, 32);
            unsigned oA1 = (unsigned)__shfl_xor((int)A1, 32);
            unsigned oA2 = (unsigned)__shfl_xor((int)A2, 32);
            unsigned oA3 = (unsigned)__shfl_xor((int)A3, 32);
            union { unsigned u[4]; bf16x8 v; } pu;
            pu.u[0] = hi ? oA2 : A0;      // keys hi*8 + (0,1)
            pu.u[1] = hi ? oA3 : A1;      // keys hi*8 + (2,3)
            pu.u[2] = hi ? A2 : oA0;      // keys hi*8 + (4,5)
            pu.u[3] = hi ? A3 : oA1;      // keys hi*8 + (6,7)
            pf[ss] = pu.v;
        }

        // O^T += V^T * P^T : D[c][q]
        __builtin_amdgcn_s_setprio(1);
#pragma unroll
        for (int ct = 0; ct < 4; ct++) {
#pragma unroll
            for (int ss = 0; ss < 4; ss++) {
                int inner = (ss * 32 + hi * 16) ^ swz;
                bf16x8 av = *reinterpret_cast<const bf16x8*>(Vc + ((ct * 32 + q32) * 128 + inner));
                oacc[ct] = mfma32(av, pf[ss], oacc[ct]);
            }
        }
        __builtin_amdgcn_s_setprio(0);
        cur ^= 1;
    }

    // epilogue: O^T lane layout -> (N,128) bf16; c = ct*32 + (t&1)*2 + (t>>1)*8 + 4*hi
    float invl = 1.f / l_run;
    size_t orow = (size_t)bi * NTOK + qbase + w * 32 + q32;
    if (S == 1) {
#pragma unroll
        for (int ct = 0; ct < 4; ct++)
#pragma unroll
            for (int t = 0; t < 8; t++) {
                int c = ct * 32 + (t & 1) * 2 + (t >> 1) * 8 + 4 * hi;
                unsigned pk = pkbf(oacc[ct][2 * t] * invl, oacc[ct][2 * t + 1] * invl);
                *reinterpret_cast<unsigned*>(&Out[orow * 128 + c]) = pk;
            }
    } else {
        size_t obase = ((size_t)s * NROW + orow) * 128;
#pragma unroll
        for (int ct = 0; ct < 4; ct++)
#pragma unroll
            for (int t = 0; t < 8; t++) {
                int c = ct * 32 + (t & 1) * 2 + (t >> 1) * 8 + 4 * hi;
                unsigned pk = pkbf(oacc[ct][2 * t] * invl, oacc[ct][2 * t + 1] * invl);
                *reinterpret_cast<unsigned*>(&Out[obase + c]) = pk;
            }
        if (hi == 0) {
            mpart[(size_t)s * NROW + orow] = m_run;
            lpart[(size_t)s * NROW + orow] = l_run;
        }
    }
}

// ---------- phase 2b: merge split-K partials (log2 domain) ----------
template<int S>
__global__ void __launch_bounds__(256)
merge_kernel(const __hip_bfloat16* __restrict__ Opart, const float* __restrict__ mpart,
             const float* __restrict__ lpart, __hip_bfloat16* __restrict__ Obf) {
    int gid = blockIdx.x * 256 + threadIdx.x;   // NROW * 16
    int row = gid >> 4;
    int c0 = (gid & 15) * 8;

    float m = -1e30f;
#pragma unroll
    for (int s = 0; s < S; s++) m = fmaxf(m, mpart[(size_t)s * NROW + row]);
    float wgt[S];
    float den = 0.f;
#pragma unroll
    for (int s = 0; s < S; s++) {
        wgt[s] = lpart[(size_t)s * NROW + row] * exp2f(mpart[(size_t)s * NROW + row] - m);
        den += wgt[s];
    }
    float o[8];
#pragma unroll
    for (int j = 0; j < 8; j++) o[j] = 0.f;
#pragma unroll
    for (int s = 0; s < S; s++) {
        bf16x8 v = *reinterpret_cast<const bf16x8*>(
            &Opart[((size_t)s * NROW + row) * 128 + c0]);
#pragma unroll
        for (int j = 0; j < 8; j++) o[j] = fmaf(wgt[s], (float)v[j], o[j]);
    }
    float invden = 1.f / den;
    bf16x8 outv;
#pragma unroll
    for (int j = 0; j < 8; j++) outv[j] = (__bf16)(o[j] * invden);
    *reinterpret_cast<bf16x8*>(&Obf[(size_t)row * 128 + c0]) = outv;
}

// ---------- phase 3: out = embed_w @ y + embed_b + feat ----------
__global__ void __launch_bounds__(256)
embed_kernel(const __hip_bfloat16* __restrict__ EWb, const __hip_bfloat16* __restrict__ Obf,
             const float* __restrict__ eb, const float* __restrict__ feat,
             float* __restrict__ out) {
    int bi = blockIdx.x / 98;
    int nc = blockIdx.x % 98;
    int nbase = nc * 64;
    int tid = threadIdx.x;
    int w = tid >> 6, lane = tid & 63, ln = lane & 15, g = lane >> 4;
    const __hip_bfloat16* Ob = Obf + (size_t)bi * NTOK * 128;

    f32x4 acc[4][4];
#pragma unroll
    for (int rt = 0; rt < 4; rt++)
#pragma unroll
        for (int ct = 0; ct < 4; ct++) acc[rt][ct] = (f32x4){0.f, 0.f, 0.f, 0.f};

#pragma unroll
    for (int ks = 0; ks < 4; ks++) {
        bf16x8 A[4], Bv[4];
#pragma unroll
        for (int rt = 0; rt < 4; rt++)
            A[rt] = *reinterpret_cast<const bf16x8*>(
                &EWb[(size_t)(w * 64 + rt * 16 + ln) * 128 + ks * 32 + g * 8]);
#pragma unroll
        for (int ct = 0; ct < 4; ct++)
            Bv[ct] = *reinterpret_cast<const bf16x8*>(
                &Ob[(size_t)(nbase + ct * 16 + ln) * 128 + ks * 32 + g * 8]);
#pragma unroll
        for (int rt = 0; rt < 4; rt++)
#pragma unroll
            for (int ct = 0; ct < 4; ct++)
                acc[rt][ct] = mfma16(A[rt], Bv[ct], acc[rt][ct]);
    }

#pragma unroll
    for (int rt = 0; rt < 4; rt++)
#pragma unroll
        for (int ct = 0; ct < 4; ct++)
#pragma unroll
            for (int r = 0; r < 4; r++) {
                int c = w * 64 + rt * 16 + g * 4 + r;
                int n = nbase + ct * 16 + ln;
                int t = n / HW, sp = n % HW;
                size_t idx = ((size_t)(bi * 8 + t) * 256 + c) * HW + sp;
                out[idx] = feat[idx] + acc[rt][ct][r] + eb[c];
            }
}

extern "C" void kernel_launch(void* const* d_in, const int* in_sizes, int n_in,
                              void* d_out, int out_size, void* d_ws, size_t ws_size,
                              hipStream_t stream) {
    const float* feat = (const float*)d_in[0];
    const float* tw   = (const float*)d_in[1];
    const float* tb   = (const float*)d_in[2];
    const float* pw   = (const float*)d_in[3];
    const float* pb   = (const float*)d_in[4];
    const float* gw   = (const float*)d_in[5];
    const float* gb   = (const float*)d_in[6];
    const float* ew   = (const float*)d_in[7];
    const float* eb   = (const float*)d_in[8];
    float* out = (float*)d_out;

    const size_t NE = (size_t)NB * NTOK * 128;  // 3,211,264 elems per buffer
    __hip_bfloat16* Q   = (__hip_bfloat16*)d_ws;
    __hip_bfloat16* K   = Q + NE;
    __hip_bfloat16* VT  = K + NE;
    __hip_bfloat16* Obf = VT + NE;
    float* wT = (float*)(Obf + NE);
    __hip_bfloat16* EWb = (__hip_bfloat16*)(wT + 3 * 32768);
    __hip_bfloat16* Opart = EWb + 32768;

    const size_t base_bytes = (size_t)((char*)(Opart) - (char*)d_ws);
    const size_t per_split = (size_t)NROW * 128 * 2 + (size_t)NROW * 8;  // O + m + l
    int S = 1;
    if (ws_size >= base_bytes + 8 * per_split) S = 8;
    else if (ws_size >= base_bytes + 4 * per_split) S = 4;
    else if (ws_size >= base_bytes + 2 * per_split) S = 2;

    float* mpart = (float*)(Opart + (size_t)S * NROW * 128);
    float* lpart = mpart + (size_t)S * NROW;

    prep_kernel<<<512, 256, 0, stream>>>(tw, pw, gw, ew, wT, EWb);
    proj_kernel<<<NB * 8 * 49, 256, 0, stream>>>(feat, wT, tb, pb, gb, Q, K, VT);

    if (S == 8) {
        attn_kernel<8><<<NB * 49 * 8, 256, 0, stream>>>(Q, K, VT, Opart, mpart, lpart);
        merge_kernel<8><<<NROW * 16 / 256, 256, 0, stream>>>(Opart, mpart, lpart, Obf);
    } else if (S == 4) {
        attn_kernel<4><<<NB * 49 * 4, 256, 0, stream>>>(Q, K, VT, Opart, mpart, lpart);
        merge_kernel<4><<<NROW * 16 / 256, 256, 0, stream>>>(Opart, mpart, lpart, Obf);
    } else if (S == 2) {
        attn_kernel<2><<<NB * 49 * 2, 256, 0, stream>>>(Q, K, VT, Opart, mpart, lpart);
        merge_kernel<2><<<NROW * 16 / 256, 256, 0, stream>>>(Opart, mpart, lpart, Obf);
    } else {
        attn_kernel<1><<<NB * 49, 256, 0, stream>>>(Q, K, VT, Obf, nullptr, nullptr);
    }

    embed_kernel<<<NB * 98, 256, 0, stream>>>(EWb, Obf, eb, feat, out);
}